// Round 7
// baseline (3782.173 us; speedup 1.0000x reference)
//
#include <hip/hip_runtime.h>
#include <cstdint>
#include <cstddef>

#define B_SZ 32
#define NPTS 16384
#define NSAMP 2048
#define F_IN 64
#define C_IN 67
#define D_OUT 128
#define FPS_THREADS 512
#define PPT 32                  // points per thread
#define NPAIR (PPT / 2)         // 16 float2 pairs
#define NWAVE (FPS_THREADS / 64)

typedef float f32x2 __attribute__((ext_vector_type(2)));

// u64-key max across a wave level via DPP on both halves.
// bound_ctrl=false + old=self => invalid lanes keep own value (max-safe).
template <int CTRL>
__device__ __forceinline__ unsigned long long dpp_key_max(unsigned long long key) {
    const int lo = (int)(unsigned)key;
    const int hi = (int)(unsigned)(key >> 32);
    const int lo2 = __builtin_amdgcn_update_dpp(lo, lo, CTRL, 0xf, 0xf, false);
    const int hi2 = __builtin_amdgcn_update_dpp(hi, hi, CTRL, 0xf, 0xf, false);
    const unsigned long long ok =
        ((unsigned long long)(unsigned)hi2 << 32) | (unsigned)(unsigned)lo2;
    return ok > key ? ok : key;
}

__device__ __forceinline__ f32x2 pk_add(f32x2 a, f32x2 b) {
    f32x2 d;
    asm("v_pk_add_f32 %0, %1, %2" : "=v"(d) : "v"(a), "v"(b));
    return d;
}
__device__ __forceinline__ f32x2 pk_sq(f32x2 a) {
    f32x2 d;
    asm("v_pk_mul_f32 %0, %1, %1" : "=v"(d) : "v"(a));
    return d;
}

// ---------------------------------------------------------------------------
// FPS: one block per batch, 512 threads, 32 pts/thread.
// px,py in VGPR f32x2 pairs; z pair-interleaved in LDS (ds_read_b64).
// Dist math: packed v_pk ops via asm (per-component rn, a+(-b) == a-b exactly,
// same (dx^2+dy^2)+dz^2 association as reference -> bit-identical trajectory).
// Reduce: per-thread inline argmax (bp in 0..31) -> u64 key
// (dist_bits<<32 | ~global_idx) -> 6-level DPP butterfly (lane63 complete) ->
// ONE barrier -> all threads redundantly max 8 wave keys -> centroid load.
// Parity key slots keep the single-barrier loop race-free.
// ---------------------------------------------------------------------------
__global__ __launch_bounds__(FPS_THREADS, 1)
void fps_kernel(const float* __restrict__ xyz,       // [B, N, 3]
                const int* __restrict__ init_far,    // [B]
                int* __restrict__ idx_out,           // [B, S]
                float* __restrict__ newxyz_out)      // [B, S, 3]
{
    const int b = blockIdx.x;
    const int tid = threadIdx.x;
    const float* base = xyz + (size_t)b * NPTS * 3;

    __shared__ f32x2 s_zp[NPAIR * FPS_THREADS];          // 64 KB
    __shared__ unsigned long long s_key[2][NWAVE];

    f32x2 px2[NPAIR], py2[NPAIR];
    float dist[PPT];
#pragma unroll
    for (int k = 0; k < NPAIR; ++k) {
        const int i0 = tid + (2 * k) * FPS_THREADS;      // ascending in (k,half)
        const int i1 = i0 + FPS_THREADS;
        px2[k] = f32x2{base[i0 * 3 + 0], base[i1 * 3 + 0]};
        py2[k] = f32x2{base[i0 * 3 + 1], base[i1 * 3 + 1]};
        s_zp[k * FPS_THREADS + tid] = f32x2{base[i0 * 3 + 2], base[i1 * 3 + 2]};
        dist[2 * k] = 1e10f;
        dist[2 * k + 1] = 1e10f;
    }

    int cur = init_far[b];
    float cx = base[cur * 3 + 0];
    float cy = base[cur * 3 + 1];
    float cz = base[cur * 3 + 2];
    __syncthreads();

    const int lane = tid & 63;
    const int wave = tid >> 6;

    for (int s = 0; s < NSAMP; ++s) {
        const int q = s & 1;
        // record BEFORE update (reference scan semantics)
        if (tid == 0) {
            idx_out[b * NSAMP + s] = cur;
            float* o = newxyz_out + (size_t)(b * NSAMP + s) * 3;
            o[0] = cx; o[1] = cy; o[2] = cz;
        }

        // negated centroid pairs: a + (-c) is bit-identical to a - c
        const f32x2 ncx2 = {-cx, -cx};
        const f32x2 ncy2 = {-cy, -cy};
        const f32x2 ncz2 = {-cz, -cz};

        float best = 0.0f;     // dists >= 0; ties -> lowest index via bp scan order
        int   bp   = 0;
#pragma unroll
        for (int k = 0; k < NPAIR; ++k) {
            const f32x2 z01 = s_zp[k * FPS_THREADS + tid];   // ds_read_b64
            const f32x2 dx = pk_add(px2[k], ncx2);
            const f32x2 dy = pk_add(py2[k], ncy2);
            const f32x2 dz = pk_add(z01,   ncz2);
            const f32x2 t0 = pk_sq(dx);
            const f32x2 t1 = pk_sq(dy);
            const f32x2 t2 = pk_sq(dz);
            const f32x2 t3 = pk_add(t0, t1);
            const f32x2 d  = pk_add(t3, t2);
            const float nd0 = fminf(dist[2 * k], d.x);
            const float nd1 = fminf(dist[2 * k + 1], d.y);
            dist[2 * k] = nd0;
            dist[2 * k + 1] = nd1;
            // ascending global index in (k,half); strict '>' -> lowest on tie
            if (nd0 > best) { best = nd0; bp = 2 * k; }
            if (nd1 > best) { best = nd1; bp = 2 * k + 1; }
        }
        const int bi = tid + bp * FPS_THREADS;

        // packed key: max dist wins; tie -> lowest global index
        unsigned long long key =
            ((unsigned long long)__float_as_uint(best) << 32) |
            (unsigned long long)(~(unsigned)bi);

        // 6-level DPP butterfly; lane 63 ends with the wave max
        key = dpp_key_max<0x111>(key);   // row_shr:1
        key = dpp_key_max<0x112>(key);   // row_shr:2
        key = dpp_key_max<0x114>(key);   // row_shr:4
        key = dpp_key_max<0x118>(key);   // row_shr:8
        key = dpp_key_max<0x142>(key);   // row_bcast:15
        key = dpp_key_max<0x143>(key);   // row_bcast:31
        if (lane == 63) s_key[q][wave] = key;
        __syncthreads();                 // the only barrier

        unsigned long long fin = s_key[q][0];
#pragma unroll
        for (int w = 1; w < NWAVE; ++w) {
            const unsigned long long k2 = s_key[q][w];
            fin = (k2 > fin) ? k2 : fin;
        }
        const int vi = (int)(~(unsigned)(fin & 0xFFFFFFFFull));
        cur = vi;
        // broadcast centroid load (uniform address, L2-resident)
        cx = base[vi * 3 + 0];
        cy = base[vi * 3 + 1];
        cz = base[vi * 3 + 2];
    }
}

// ---------------------------------------------------------------------------
// Kernel 2: gather selected rows, 1x1 conv (x @ W + b), ReLU.
// ---------------------------------------------------------------------------
#define SAMP_PER_BLK 16

__global__ __launch_bounds__(256)
void gather_linear_relu_kernel(const float* __restrict__ xyz,    // [B,N,3]
                               const float* __restrict__ feats,  // [B,N,F]
                               const int* __restrict__ idx,      // [B*S]
                               const float* __restrict__ W,      // [67,128]
                               const float* __restrict__ bias,   // [128]
                               float* __restrict__ out)          // [B*S,128]
{
    __shared__ float sW[C_IN][D_OUT];
    __shared__ float sX[SAMP_PER_BLK][C_IN + 1];
    __shared__ float sB[D_OUT];

    const int tid = threadIdx.x;

    for (int i = tid; i < C_IN * D_OUT; i += 256)
        (&sW[0][0])[i] = W[i];
    if (tid < D_OUT) sB[tid] = bias[tid];

    const int gs0 = blockIdx.x * SAMP_PER_BLK;

    {
        const int si = tid >> 4;
        const int j  = tid & 15;
        const int gs = gs0 + si;
        const int bb = gs >> 11;
        const int pt = idx[gs];
        const float* frow = feats + ((size_t)bb * NPTS + pt) * F_IN;
        const float* xrow = xyz   + ((size_t)bb * NPTS + pt) * 3;
        for (int c = j; c < F_IN; c += 16) sX[si][c] = frow[c];
        if (j < 3) sX[si][F_IN + j] = xrow[j];
    }
    __syncthreads();

    const int d = tid & 127;
    const int g = tid >> 7;
    float acc[8];
#pragma unroll
    for (int k = 0; k < 8; ++k) acc[k] = 0.0f;

    for (int c = 0; c < C_IN; ++c) {
        const float w = sW[c][d];
#pragma unroll
        for (int k = 0; k < 8; ++k)
            acc[k] = fmaf(sX[g * 8 + k][c], w, acc[k]);
    }

    const float bv = sB[d];
#pragma unroll
    for (int k = 0; k < 8; ++k) {
        const int gs = gs0 + g * 8 + k;
        const float v = acc[k] + bv;
        out[(size_t)gs * D_OUT + d] = fmaxf(v, 0.0f);
    }
}

// ---------------------------------------------------------------------------
extern "C" void kernel_launch(void* const* d_in, const int* in_sizes, int n_in,
                              void* d_out, int out_size, void* d_ws, size_t ws_size,
                              hipStream_t stream) {
    const float* xyz      = (const float*)d_in[0];
    const float* feats    = (const float*)d_in[1];
    const int*   init_far = (const int*)d_in[2];
    const float* W        = (const float*)d_in[3];
    const float* bias     = (const float*)d_in[4];

    float* out_newxyz = (float*)d_out;
    float* out_conv   = (float*)d_out + (size_t)B_SZ * NSAMP * 3;
    int*   idx_ws     = (int*)d_ws;

    fps_kernel<<<B_SZ, FPS_THREADS, 0, stream>>>(xyz, init_far, idx_ws, out_newxyz);

    const int nblocks = (B_SZ * NSAMP) / SAMP_PER_BLK;
    gather_linear_relu_kernel<<<nblocks, 256, 0, stream>>>(
        xyz, feats, idx_ws, W, bias, out_conv);
}

// Round 8
// 3515.018 us; speedup vs baseline: 1.0760x; 1.0760x over previous
//
#include <hip/hip_runtime.h>
#include <cstdint>
#include <cstddef>

#define B_SZ 32
#define NPTS 16384
#define NSAMP 2048
#define F_IN 64
#define C_IN 67
#define D_OUT 128
#define FPS_THREADS 1024
#define PPT 16                  // points per thread
#define NWAVE (FPS_THREADS / 64)   // 16

// u64-key max across a wave level via DPP on both halves.
// bound_ctrl=false + old=self => invalid lanes keep own value (max-safe).
template <int CTRL>
__device__ __forceinline__ unsigned long long dpp_key_max(unsigned long long key) {
    const int lo = (int)(unsigned)key;
    const int hi = (int)(unsigned)(key >> 32);
    const int lo2 = __builtin_amdgcn_update_dpp(lo, lo, CTRL, 0xf, 0xf, false);
    const int hi2 = __builtin_amdgcn_update_dpp(hi, hi, CTRL, 0xf, 0xf, false);
    const unsigned long long ok =
        ((unsigned long long)(unsigned)hi2 << 32) | (unsigned)(unsigned)lo2;
    return ok > key ? ok : key;
}

// ---------------------------------------------------------------------------
// FPS: one block per batch, 1024 threads, 16 pts/thread — ALL state in VGPRs
// (64 floats), 4 waves/SIMD for latency hiding.
// Per iteration (ONE barrier):
//   A. dist update, explicit rn ops (bit-matches reference), value-only
//      running max (shortest dep chain; no per-point index cndmask).
//   B. local rescan (downward) for own first-match bp -> global index bi.
//      All threads do this; no divergence, no atomics.
//   C. u64 key = dist_bits<<32 | ~bi  (max dist, tie -> lowest index,
//      exactly jnp.argmax first-occurrence).
//   D. 6-level DPP butterfly -> lane63 holds wave max; write LDS[parity].
//   E. __syncthreads(); all threads redundantly max the 16 wave keys.
//   F. broadcast centroid load (uniform address, L2-resident).
// ---------------------------------------------------------------------------
__global__ __launch_bounds__(FPS_THREADS, 4)
void fps_kernel(const float* __restrict__ xyz,       // [B, N, 3]
                const int* __restrict__ init_far,    // [B]
                int* __restrict__ idx_out,           // [B, S]
                float* __restrict__ newxyz_out)      // [B, S, 3]
{
    const int b = blockIdx.x;
    const int tid = threadIdx.x;
    const float* base = xyz + (size_t)b * NPTS * 3;

    __shared__ unsigned long long s_key[2][NWAVE];

    float px[PPT], py[PPT], pz[PPT], dist[PPT];
#pragma unroll
    for (int p = 0; p < PPT; ++p) {
        const int i = tid + p * FPS_THREADS;     // ascending global index in p
        px[p] = base[i * 3 + 0];
        py[p] = base[i * 3 + 1];
        pz[p] = base[i * 3 + 2];
        dist[p] = 1e10f;
    }

    int cur = init_far[b];
    float cx = base[cur * 3 + 0];
    float cy = base[cur * 3 + 1];
    float cz = base[cur * 3 + 2];
    __syncthreads();

    const int lane = tid & 63;
    const int wave = tid >> 6;

    for (int s = 0; s < NSAMP; ++s) {
        const int q = s & 1;
        // record BEFORE update (reference scan semantics); fire-and-forget
        if (tid == 0) {
            idx_out[b * NSAMP + s] = cur;
            float* o = newxyz_out + (size_t)(b * NSAMP + s) * 3;
            o[0] = cx; o[1] = cy; o[2] = cz;
        }

        // A: distance update + value-only running max
        float best = 0.0f;
#pragma unroll
        for (int p = 0; p < PPT; ++p) {
            const float dx = __fsub_rn(px[p], cx);
            const float dy = __fsub_rn(py[p], cy);
            const float dz = __fsub_rn(pz[p], cz);
            const float d  = __fadd_rn(__fadd_rn(__fmul_rn(dx, dx),
                                                 __fmul_rn(dy, dy)),
                                       __fmul_rn(dz, dz));
            const float nd = fminf(dist[p], d);
            dist[p] = nd;
            best = fmaxf(best, nd);
        }

        // B: local rescan, downward -> smallest p with dist[p]==best
        int bp = 0;
#pragma unroll
        for (int p = PPT - 1; p >= 0; --p)
            bp = (dist[p] == best) ? p : bp;
        const int bi = tid + bp * FPS_THREADS;

        // C: packed key (max dist; tie -> lowest global index)
        unsigned long long key =
            ((unsigned long long)__float_as_uint(best) << 32) |
            (unsigned long long)(~(unsigned)bi);

        // D: 6-level DPP butterfly; lane 63 complete
        key = dpp_key_max<0x111>(key);   // row_shr:1
        key = dpp_key_max<0x112>(key);   // row_shr:2
        key = dpp_key_max<0x114>(key);   // row_shr:4
        key = dpp_key_max<0x118>(key);   // row_shr:8
        key = dpp_key_max<0x142>(key);   // row_bcast:15
        key = dpp_key_max<0x143>(key);   // row_bcast:31
        if (lane == 63) s_key[q][wave] = key;
        __syncthreads();                 // the only barrier

        // E: redundant block reduce over 16 wave keys
        unsigned long long fin = s_key[q][0];
#pragma unroll
        for (int w = 1; w < NWAVE; ++w) {
            const unsigned long long k2 = s_key[q][w];
            fin = (k2 > fin) ? k2 : fin;
        }
        const int vi = (int)(~(unsigned)(fin & 0xFFFFFFFFull));
        cur = vi;
        // F: broadcast centroid load (uniform address, L2-resident)
        cx = base[vi * 3 + 0];
        cy = base[vi * 3 + 1];
        cz = base[vi * 3 + 2];
    }
}

// ---------------------------------------------------------------------------
// Kernel 2: gather selected rows, 1x1 conv (x @ W + b), ReLU.
// ---------------------------------------------------------------------------
#define SAMP_PER_BLK 16

__global__ __launch_bounds__(256)
void gather_linear_relu_kernel(const float* __restrict__ xyz,    // [B,N,3]
                               const float* __restrict__ feats,  // [B,N,F]
                               const int* __restrict__ idx,      // [B*S]
                               const float* __restrict__ W,      // [67,128]
                               const float* __restrict__ bias,   // [128]
                               float* __restrict__ out)          // [B*S,128]
{
    __shared__ float sW[C_IN][D_OUT];
    __shared__ float sX[SAMP_PER_BLK][C_IN + 1];
    __shared__ float sB[D_OUT];

    const int tid = threadIdx.x;

    for (int i = tid; i < C_IN * D_OUT; i += 256)
        (&sW[0][0])[i] = W[i];
    if (tid < D_OUT) sB[tid] = bias[tid];

    const int gs0 = blockIdx.x * SAMP_PER_BLK;

    {
        const int si = tid >> 4;
        const int j  = tid & 15;
        const int gs = gs0 + si;
        const int bb = gs >> 11;
        const int pt = idx[gs];
        const float* frow = feats + ((size_t)bb * NPTS + pt) * F_IN;
        const float* xrow = xyz   + ((size_t)bb * NPTS + pt) * 3;
        for (int c = j; c < F_IN; c += 16) sX[si][c] = frow[c];
        if (j < 3) sX[si][F_IN + j] = xrow[j];
    }
    __syncthreads();

    const int d = tid & 127;
    const int g = tid >> 7;
    float acc[8];
#pragma unroll
    for (int k = 0; k < 8; ++k) acc[k] = 0.0f;

    for (int c = 0; c < C_IN; ++c) {
        const float w = sW[c][d];
#pragma unroll
        for (int k = 0; k < 8; ++k)
            acc[k] = fmaf(sX[g * 8 + k][c], w, acc[k]);
    }

    const float bv = sB[d];
#pragma unroll
    for (int k = 0; k < 8; ++k) {
        const int gs = gs0 + g * 8 + k;
        const float v = acc[k] + bv;
        out[(size_t)gs * D_OUT + d] = fmaxf(v, 0.0f);
    }
}

// ---------------------------------------------------------------------------
extern "C" void kernel_launch(void* const* d_in, const int* in_sizes, int n_in,
                              void* d_out, int out_size, void* d_ws, size_t ws_size,
                              hipStream_t stream) {
    const float* xyz      = (const float*)d_in[0];
    const float* feats    = (const float*)d_in[1];
    const int*   init_far = (const int*)d_in[2];
    const float* W        = (const float*)d_in[3];
    const float* bias     = (const float*)d_in[4];

    float* out_newxyz = (float*)d_out;
    float* out_conv   = (float*)d_out + (size_t)B_SZ * NSAMP * 3;
    int*   idx_ws     = (int*)d_ws;

    fps_kernel<<<B_SZ, FPS_THREADS, 0, stream>>>(xyz, init_far, idx_ws, out_newxyz);

    const int nblocks = (B_SZ * NSAMP) / SAMP_PER_BLK;
    gather_linear_relu_kernel<<<nblocks, 256, 0, stream>>>(
        xyz, feats, idx_ws, W, bias, out_conv);
}